// Round 10
// baseline (286.123 us; speedup 1.0000x reference)
//
#include <hip/hip_runtime.h>

// Conv1d: x (32, 64, 16384) f32, w (64, 64, 3) f32, bias (64) f32
// -> out (32, 64, 16382) f32, VALID, stride 1.
// GEMM view: out[co][n] = sum_kappa A[co][kappa] * B[kappa][n] + bias[co]
//   kappa = kk*64 + ci (kk-major). B[kappa][n] = x[ci][n+kk]; kk shift applied
//   at LDS-read time (col+kk) so each x element is staged once.
//
// R8 = R7 (108us rocprof) + barrier-drain fix. Key insight: __syncthreads()
// emits s_waitcnt vmcnt(0) before s_barrier -> every phase drained the
// "prefetched" loads AND the output stores: the T14 overlap never happened
// (32K cyc/phase measured vs ~6K of work). Fixes:
//  1. lgkm-only barrier (s_waitcnt lgkmcnt(0); s_barrier): LDS visibility
//     preserved, global loads/stores stay in flight across phases.
//  2. Depth-2 prefetch (sva/svb): loads for ss+2 issued at ss, LDS-written
//     at ss+1 -> a full phase to land; compiler's counted vmcnt at the
//     write waits only on the old batch (T4 via register deps).
//  3. xt double-buffered -> ONE barrier per phase (was 2).
// Register budget: 34 sv + 16 AGPR acc + ~45 addr = ~95 unified < 128 cap.
// LDS 45.4KB -> 3 blocks/CU (latency hidden by ILP now, not TLP).

typedef __bf16 bf16x8 __attribute__((ext_vector_type(8)));
typedef float f32x16 __attribute__((ext_vector_type(16)));

#define C_IN 64
#define C_OUT 64
#define L_IN 16384
#define L_OUT 16382
#define NT 64            // cols per phase
#define SUBT 8           // phases per block
#define BT (NT * SUBT)   // 512 cols per block
#define PW 200           // wl row pitch: >=192, 16B-aligned rows, 4-way floor
#define XT_P 72          // xt row pitch: 144B = 16B-aligned b128, 4-way floor
#define XT_COLS 68       // 64 cols + 2 halo + 2 pad; 64*68 = 17*256 exact
#define NLOAD 17         // staging elems per thread per phase

__device__ __forceinline__ void barrier_lgkm() {
  // LDS-visibility barrier WITHOUT the vmcnt(0) drain __syncthreads adds.
  asm volatile("s_waitcnt lgkmcnt(0)" ::: "memory");
  __builtin_amdgcn_s_barrier();
}

__global__ __launch_bounds__(256, 3) void conv1d_mfma(
    const float* __restrict__ x, const float* __restrict__ w,
    const float* __restrict__ bias, float* __restrict__ out) {
  __shared__ __align__(16) __bf16 wl[C_OUT * PW];       // 25600 B
  __shared__ __align__(16) __bf16 xtA[XT_COLS * XT_P];  // 9792 B
  __shared__ __align__(16) __bf16 xtB[XT_COLS * XT_P];  // 9792 B
  __shared__ float bias_s[C_OUT];                       // 256 B (45440 total)

  const int t = threadIdx.x;
  const int bx = blockIdx.x;
  const int b = bx >> 5;        // batch
  const int tile = bx & 31;     // 512-col tile
  const int l0 = tile * BT;
  const float* xb = x + (size_t)b * (C_IN * L_IN);

  const int lane = t & 63;
  const int wv = t >> 6;
  const int coh = wv >> 1;      // co-half   (wave tile: 32 co x 32 col)
  const int colh = wv & 1;      // col-half
  const int half = lane >> 5;   // k-half within fragment
  const int ln = lane & 31;
  const int kh = half * 8;

  // Staging map: idx = t + k*256 -> (ci = idx/68, col = idx%68).
  // Consecutive lanes -> consecutive cols: coalesced 272B global runs;
  // LDS writes bank-stride 4 (~4-way max).
#define STAGE_LOAD(BASE, SV, CL)                                \
  _Pragma("unroll") for (int k = 0; k < NLOAD; ++k) {           \
    int idx = t + k * 256;                                      \
    int ci = idx / XT_COLS;                                     \
    int col = idx - ci * XT_COLS;                               \
    int gc = (BASE) + col;                                      \
    if (CL) gc = min(gc, L_IN - 1); /* junk feeds unstored cols only */ \
    SV[k] = xb[(size_t)ci * L_IN + gc];                         \
  }

#define STAGE_WRITE(BUF, SV)                                    \
  _Pragma("unroll") for (int k = 0; k < NLOAD; ++k) {           \
    int idx = t + k * 256;                                      \
    int ci = idx / XT_COLS;                                     \
    int col = idx - ci * XT_COLS;                                \
    BUF[col * XT_P + ci] = (__bf16)SV[k];                       \
  }

  float sva[NLOAD], svb[NLOAD];

  // ---- prologue: phase-0 data -> xtA; phase-1 loads left IN FLIGHT.
  STAGE_LOAD(l0, sva, 0)               // max col 16003 < L_IN: no clamp
  STAGE_LOAD(l0 + NT, svb, 0)
  for (int i = t; i < C_OUT * 192; i += 256) {   // wl[co][kk*64+ci]
    int co = i / 192;
    int r = i - co * 192;
    int ci = r / 3;
    int kk = r - ci * 3;
    wl[co * PW + kk * 64 + ci] = (__bf16)w[i];
  }
  if (t < C_OUT) bias_s[t] = bias[t];
  STAGE_WRITE(xtA, sva)                // vmcnt-waits on sva batch only
  barrier_lgkm();

  // ---- phases. SVW: data for SS+1 (loaded at SS-1). SVL: loads for SS+2.
#define PHASE(CUR, NXT, SVW, SVL, SS)                                       \
  {                                                                         \
    if ((SS) + 2 < SUBT) {                                                  \
      if ((SS) == 5 && tile == 31) { STAGE_LOAD(l0 + ((SS) + 2) * NT, SVL, 1) } \
      else                         { STAGE_LOAD(l0 + ((SS) + 2) * NT, SVL, 0) } \
    }                                                                       \
    f32x16 acc = {};                                                        \
    _Pragma("unroll") for (int s = 0; s < 12; ++s) {                        \
      int kap = s * 16 + kh;                                                \
      int kk = kap >> 6;           /* uniform over the 8-elem fragment */   \
      int ci0 = kap & 63;                                                   \
      bf16x8 av = *(const bf16x8*)&wl[(coh * 32 + ln) * PW + kap];          \
      bf16x8 bv = *(const bf16x8*)&CUR[(colh * 32 + ln + kk) * XT_P + ci0]; \
      acc = __builtin_amdgcn_mfma_f32_32x32x16_bf16(av, bv, acc, 0, 0, 0);  \
    }                                                                       \
    {                                                                       \
      int ng = l0 + (SS) * NT + colh * 32 + ln;                             \
      bool tail = (tile == 31 && (SS) == SUBT - 1);  /* wave-uniform */     \
      if (!tail || ng < L_OUT) {                                            \
        _Pragma("unroll") for (int r = 0; r < 16; ++r) {                    \
          int cl = 4 * half + (r & 3) + 8 * (r >> 2);                       \
          int co = coh * 32 + cl;                                           \
          out[(size_t)(b * C_OUT + co) * L_OUT + ng] = acc[r] + bias_s[co]; \
        }                                                                   \
      }                                                                     \
    }                                                                       \
    if ((SS) + 1 < SUBT) { STAGE_WRITE(NXT, SVW) }                          \
    barrier_lgkm();                                                         \
  }

  PHASE(xtA, xtB, svb, sva, 0)
  PHASE(xtB, xtA, sva, svb, 1)
  PHASE(xtA, xtB, svb, sva, 2)
  PHASE(xtB, xtA, sva, svb, 3)
  PHASE(xtA, xtB, svb, sva, 4)
  PHASE(xtB, xtA, sva, svb, 5)
  PHASE(xtA, xtB, svb, sva, 6)
  PHASE(xtB, xtA, sva, svb, 7)
#undef PHASE
#undef STAGE_LOAD
#undef STAGE_WRITE
}

extern "C" void kernel_launch(void* const* d_in, const int* in_sizes, int n_in,
                              void* d_out, int out_size, void* d_ws, size_t ws_size,
                              hipStream_t stream) {
  const float* x = (const float*)d_in[0];
  const float* w = (const float*)d_in[1];
  const float* bias = (const float*)d_in[2];
  float* out = (float*)d_out;
  // 32 batches * 32 tiles of 512 columns = 1024 blocks (3/CU resident + tail)
  conv1d_mfma<<<dim3(32 * 32), dim3(256), 0, stream>>>(x, w, bias, out);
}